// Round 1
// baseline (208.098 us; speedup 1.0000x reference)
//
#include <hip/hip_runtime.h>

#define NCH 23

// Class frequencies W; weights derived in-kernel with the same fp32 op order
// as the reference: w0 = 1/(W+1); w1 = 1 - w0; weights used are 1/w0, 1/w1.
__device__ __constant__ float d_W[NCH] = {
    0.0012597430655963838f, 0.0004919313290455535f, 0.0021106513104319356f,
    0.0007678117365508301f, 0.004719881670572202f,  0.000372272357115554f,
    0.029090425620315438f,  0.010056339432617042f,  0.0034817436971298467f,
    0.0003057951504877765f, 0.003995280118329428f,  8.808229878180519e-05f,
    0.012070598793438699f,  0.016788818533845208f,  0.0017832510677901316f,
    0.0008758371973209686f, 0.0005933090691529143f, 0.0031992155689617922f,
    0.003212511010287348f,  0.0016685778863572154f, 0.0009356666832859684f,
    0.0010985358395240233f, 0.00103372056306194f
};

__device__ __forceinline__ void accum_elem(float xx, int lab, unsigned c,
                                           const float* s_w0, const float* s_w1,
                                           float& acc) {
    bool t = lab > 0;
    float v = t ? xx : 1.0f - xx;
    float w = t ? s_w1[c] : s_w0[c];
    acc -= w * __logf(v);
}

__global__ __launch_bounds__(256) void bce_reduce_kernel(
        const float* __restrict__ x, const int* __restrict__ labels,
        double* __restrict__ partial, unsigned n /* total elements */) {
    __shared__ float s_w0[NCH];
    __shared__ float s_w1[NCH];
    __shared__ float s_part[4];  // 256 threads / 64-lane waves

    if (threadIdx.x < NCH) {
        float W  = d_W[threadIdx.x];
        float w0 = 1.0f / (W + 1.0f);   // _WEIGHT_0
        float w1 = 1.0f - w0;           // _WEIGHT_1
        s_w0[threadIdx.x] = 1.0f / w0;  // weight when target == 0
        s_w1[threadIdx.x] = 1.0f / w1;  // weight when target == 1
    }
    __syncthreads();

    const unsigned n4 = n >> 2;  // n == 23e6, divisible by 4
    const unsigned stride = gridDim.x * blockDim.x;
    float acc = 0.0f;

    for (unsigned k = blockIdx.x * blockDim.x + threadIdx.x; k < n4; k += stride) {
        float4 xv = ((const float4*)x)[k];
        int4   lv = ((const int4*)labels)[k];
        unsigned c = (4u * k) % 23u;                 // channel of first lane-elem
        accum_elem(xv.x, lv.x, c, s_w0, s_w1, acc);  c = (c + 1u == 23u) ? 0u : c + 1u;
        accum_elem(xv.y, lv.y, c, s_w0, s_w1, acc);  c = (c + 1u == 23u) ? 0u : c + 1u;
        accum_elem(xv.z, lv.z, c, s_w0, s_w1, acc);  c = (c + 1u == 23u) ? 0u : c + 1u;
        accum_elem(xv.w, lv.w, c, s_w0, s_w1, acc);
    }

    // Scalar tail (n % 4 != 0 safety; no-op for 23e6).
    unsigned tail_start = n4 << 2;
    for (unsigned i = tail_start + blockIdx.x * blockDim.x + threadIdx.x; i < n;
         i += stride) {
        accum_elem(x[i], labels[i], i % 23u, s_w0, s_w1, acc);
    }

    // Wave (64-lane) shuffle reduce, then LDS across the 4 waves.
    #pragma unroll
    for (int off = 32; off > 0; off >>= 1) acc += __shfl_down(acc, off, 64);
    int wave = threadIdx.x >> 6;
    int lane = threadIdx.x & 63;
    if (lane == 0) s_part[wave] = acc;
    __syncthreads();
    if (threadIdx.x == 0) {
        float s = s_part[0] + s_part[1] + s_part[2] + s_part[3];
        atomicAdd(partial, (double)s);
    }
}

__global__ void bce_finalize_kernel(const double* __restrict__ partial,
                                    float* __restrict__ out, unsigned n) {
    out[0] = (float)(partial[0] / (double)n);
}

extern "C" void kernel_launch(void* const* d_in, const int* in_sizes, int n_in,
                              void* d_out, int out_size, void* d_ws, size_t ws_size,
                              hipStream_t stream) {
    const float* x      = (const float*)d_in[0];
    const int*   labels = (const int*)d_in[1];
    float*       out    = (float*)d_out;
    double*      acc    = (double*)d_ws;
    unsigned n = (unsigned)in_sizes[0];  // B*C = 23,000,000

    hipMemsetAsync(acc, 0, sizeof(double), stream);

    const int block = 256;
    const int grid  = 2048;  // 8192 waves = full 256-CU occupancy at 32 waves/CU
    bce_reduce_kernel<<<grid, block, 0, stream>>>(x, labels, acc, n);
    bce_finalize_kernel<<<1, 1, 0, stream>>>(acc, out, n);
}